// Round 4
// baseline (1154.165 us; speedup 1.0000x reference)
//
#include <hip/hip_runtime.h>
#include <hip/hip_bf16.h>

#define NCLS 1000
#define BIMG 256
#define LSEQ 12
#define PFX  5
#define DMOD 512
#define NHEAD 8
#define NLAY 2
#define DFF  2048
#define DHEAD 64

typedef __attribute__((ext_vector_type(8))) short bf16x8;
typedef __attribute__((ext_vector_type(4))) float f32x4;

__device__ __forceinline__ float gelu_tanh(float x) {
    const float c = 0.7978845608028654f;
    float t = tanhf(c * (x + 0.044715f * x * x * x));
    return 0.5f * x * (1.0f + t);
}

__device__ __forceinline__ float bf2f(unsigned short u) {
    unsigned int x = ((unsigned int)u) << 16;
    float f; __builtin_memcpy(&f, &x, 4); return f;
}

__device__ __forceinline__ short f2bf_s(float f) {
    __hip_bfloat16 h = __float2bfloat16(f);
    short s; __builtin_memcpy(&s, &h, 2); return s;
}

__device__ __forceinline__ void gload_lds16(const void* g, void* l) {
    __builtin_amdgcn_global_load_lds(
        (const __attribute__((address_space(1))) void*)g,
        (__attribute__((address_space(3))) void*)l, 16, 0, 0);
}

// ---------------- bf16 MFMA GEMM: m97 structure + 3-deep counted-vmcnt pipeline + XCD swizzle ----
// C = A(MxK bf16, row-major) @ B (supplied as Bt = N x K bf16 row-major)
// 128x128 tile, BK=32, 4 waves (2x2), each wave 64x64 via 4x4 16x16x32 MFMA.
// EPI: 0=+bias->bf16 ; 1=+bias,gelu->bf16 ; 2=+bias,+R->f32 ; 3=exp(ls)*sM*sN->f32 (gn<Nreal guard)
template <int EPI>
__global__ __launch_bounds__(256) void gemm_mfma(
    const __hip_bfloat16* __restrict__ A, int lda,
    const __hip_bfloat16* __restrict__ Bt, int ldb,
    const float* __restrict__ bias,
    const float* __restrict__ R, int ldr,
    float* __restrict__ Cf, int ldcf,
    __hip_bfloat16* __restrict__ Cb, int ldcb,
    int M, int K, int Nreal,
    const float* __restrict__ scaleM,
    const float* __restrict__ scaleN,
    const float* __restrict__ lsp)
{
    __shared__ unsigned short As[3][128 * 32];
    __shared__ unsigned short Bs[3][128 * 32];
    const int t    = threadIdx.x;
    const int wid  = t >> 6, lane = t & 63;
    const int wm   = wid >> 1, wn = wid & 1;
    const int lr   = lane & 15, lk = lane >> 4;

    // bijective XCD swizzle (m204): consecutive same-XCD blocks share bn -> B panel L2 reuse
    const unsigned int gx = gridDim.x, gy = gridDim.y;
    const unsigned int nwg = gx * gy;
    const unsigned int orig = blockIdx.y * gx + blockIdx.x;
    const unsigned int q8 = nwg >> 3, r8 = nwg & 7;
    const unsigned int xcd = orig & 7, slot = orig >> 3;
    const unsigned int wgid = (xcd < r8 ? xcd * (q8 + 1) : r8 * (q8 + 1) + (xcd - r8) * q8) + slot;
    const int bn = (int)(wgid / gy) * 128;
    const int bm = (int)(wgid % gy) * 128;

    const int srow   = t >> 2;        // 0..63 staging row per round
    const int schunk = (t & 3) * 8;   // element offset within BK=32

    f32x4 acc[4][4] = {};

    const __hip_bfloat16* Abase = A  + (size_t)bm * lda;
    const __hip_bfloat16* Bbase = Bt + (size_t)bn * ldb;

    auto STAGE = [&](int k0, int buf) {
        char* ab = (char*)&As[buf][0];
        char* bb = (char*)&Bs[buf][0];
        gload_lds16(Abase + (size_t)srow        * lda + k0 + schunk, ab + wid * 1024);
        gload_lds16(Abase + (size_t)(srow + 64) * lda + k0 + schunk, ab + 4096 + wid * 1024);
        gload_lds16(Bbase + (size_t)srow        * ldb + k0 + schunk, bb + wid * 1024);
        gload_lds16(Bbase + (size_t)(srow + 64) * ldb + k0 + schunk, bb + 4096 + wid * 1024);
    };

    const int NIT = K >> 5;
    STAGE(0, 0);
    if (NIT > 1) {
        STAGE(32, 1);
        asm volatile("s_waitcnt vmcnt(4)" ::: "memory");   // stage(0) landed
    } else {
        asm volatile("s_waitcnt vmcnt(0)" ::: "memory");
    }
    __builtin_amdgcn_s_barrier();

    for (int it = 0; it < NIT; it++) {
        if (it + 2 < NIT) STAGE((it + 2) << 5, (it + 2) % 3);

        const unsigned short* Ab = &As[it % 3][0];
        const unsigned short* Bb = &Bs[it % 3][0];
        bf16x8 a[4], b[4];
        #pragma unroll
        for (int i = 0; i < 4; i++)
            a[i] = *reinterpret_cast<const bf16x8*>(&Ab[(wm * 64 + i * 16 + lr) * 32 + lk * 8]);
        #pragma unroll
        for (int j = 0; j < 4; j++)
            b[j] = *reinterpret_cast<const bf16x8*>(&Bb[(wn * 64 + j * 16 + lr) * 32 + lk * 8]);
        #pragma unroll
        for (int i = 0; i < 4; i++)
            #pragma unroll
            for (int j = 0; j < 4; j++)
                acc[i][j] = __builtin_amdgcn_mfma_f32_16x16x32_bf16(a[i], b[j], acc[i][j], 0, 0, 0);

        // next buffer's stage must be complete; keep the one after in flight
        if (it + 2 < NIT) asm volatile("s_waitcnt vmcnt(4)" ::: "memory");
        else              asm volatile("s_waitcnt vmcnt(0)" ::: "memory");
        __builtin_amdgcn_s_barrier();
    }

    // C/D layout (m89-verified): col = lane&15, row = (lane>>4)*4 + reg
    const float lsv = (EPI == 3) ? expf(lsp[0]) : 0.f;
    #pragma unroll
    for (int i = 0; i < 4; i++) {
        int gm0 = bm + wm * 64 + i * 16 + lk * 4;
        #pragma unroll
        for (int j = 0; j < 4; j++) {
            int gn = bn + wn * 64 + j * 16 + lr;
            float bv = (EPI <= 2 && bias) ? bias[gn] : 0.f;
            #pragma unroll
            for (int q = 0; q < 4; q++) {
                int gm = gm0 + q;
                if (gm >= M) continue;
                float v = acc[i][j][q] + bv;
                if (EPI == 1) v = gelu_tanh(v);
                if (EPI == 2) {
                    Cf[(size_t)gm * ldcf + gn] = v + R[(size_t)gm * ldr + gn];
                } else if (EPI == 3) {
                    if (gn < Nreal)
                        Cf[(size_t)gm * ldcf + gn] = lsv * scaleM[gm] * scaleN[gn] * acc[i][j][q];
                } else {
                    Cb[(size_t)gm * ldcb + gn] = __float2bfloat16(v);
                }
            }
        }
    }
}

// ---------------- weight transpose + f32->bf16: W (rows x cols) -> Wt (cols x rows) ----------------
__global__ __launch_bounds__(256) void transposeW(
    const float* __restrict__ W, int rows, int cols, __hip_bfloat16* __restrict__ Wt)
{
    __shared__ float tile[32][33];
    int bc = blockIdx.x * 32;
    int br = blockIdx.y * 32;
    int tx = threadIdx.x & 31, ty = threadIdx.x >> 5;
    #pragma unroll
    for (int i = 0; i < 4; i++) {
        int r = ty + i * 8;
        tile[r][tx] = W[(size_t)(br + r) * cols + bc + tx];
    }
    __syncthreads();
    #pragma unroll
    for (int i = 0; i < 4; i++) {
        int r = ty + i * 8;
        Wt[(size_t)(bc + r) * rows + br + tx] = __float2bfloat16(tile[tx][r]);
    }
}

// ---------------- LayerNorm: wave-per-row (4 rows/block), float4 loads, bf16x8 store ----------------
__global__ __launch_bounds__(256) void ln_bf16(
    const float* __restrict__ x, const float* __restrict__ g,
    const float* __restrict__ b, __hip_bfloat16* __restrict__ o)
{
    const int lane = threadIdx.x & 63;
    const int r = blockIdx.x * 4 + (threadIdx.x >> 6);
    const float4* xr = (const float4*)(x + (size_t)r * DMOD);
    float4 u = xr[lane * 2], v = xr[lane * 2 + 1];
    float s  = u.x + u.y + u.z + u.w + v.x + v.y + v.z + v.w;
    float qq = u.x*u.x + u.y*u.y + u.z*u.z + u.w*u.w
             + v.x*v.x + v.y*v.y + v.z*v.z + v.w*v.w;
    #pragma unroll
    for (int off = 32; off > 0; off >>= 1) {
        s  += __shfl_xor(s,  off, 64);
        qq += __shfl_xor(qq, off, 64);
    }
    float mean = s * (1.0f / DMOD);
    float inv  = rsqrtf(qq * (1.0f / DMOD) - mean * mean + 1e-5f);
    const float4* g4 = (const float4*)g;
    const float4* b4 = (const float4*)b;
    float4 ga = g4[lane * 2], gb = g4[lane * 2 + 1];
    float4 ba = b4[lane * 2], bb = b4[lane * 2 + 1];
    bf16x8 o8;
    o8[0] = f2bf_s((u.x - mean) * inv * ga.x + ba.x);
    o8[1] = f2bf_s((u.y - mean) * inv * ga.y + ba.y);
    o8[2] = f2bf_s((u.z - mean) * inv * ga.z + ba.z);
    o8[3] = f2bf_s((u.w - mean) * inv * ga.w + ba.w);
    o8[4] = f2bf_s((v.x - mean) * inv * gb.x + bb.x);
    o8[5] = f2bf_s((v.y - mean) * inv * gb.y + bb.y);
    o8[6] = f2bf_s((v.z - mean) * inv * gb.z + bb.z);
    o8[7] = f2bf_s((v.w - mean) * inv * gb.w + bb.w);
    *reinterpret_cast<bf16x8*>(&o[(size_t)r * DMOD + lane * 8]) = o8;
}

// ---------------- inverse L2 row norm, fp32 input ----------------
__global__ __launch_bounds__(256) void rownorm_inv(
    const float* __restrict__ x, float* __restrict__ inv)
{
    const int r = blockIdx.x, t = threadIdx.x;
    const float* xr = x + (size_t)r * DMOD;
    float v0 = xr[t], v1 = xr[t + 256];
    __shared__ float rq[256];
    rq[t] = v0 * v0 + v1 * v1;
    __syncthreads();
    for (int off = 128; off > 0; off >>= 1) {
        if (t < off) rq[t] += rq[t + off];
        __syncthreads();
    }
    if (t == 0) inv[r] = rsqrtf(rq[0]);
}

// ---------------- inverse L2 row norm, bf16 input ----------------
__global__ __launch_bounds__(256) void rownorm_inv_bf16(
    const __hip_bfloat16* __restrict__ x, float* __restrict__ inv)
{
    const int r = blockIdx.x, t = threadIdx.x;
    const unsigned short* xr = (const unsigned short*)(x + (size_t)r * DMOD);
    float v0 = bf2f(xr[t]), v1 = bf2f(xr[t + 256]);
    __shared__ float rq[256];
    rq[t] = v0 * v0 + v1 * v1;
    __syncthreads();
    for (int off = 128; off > 0; off >>= 1) {
        if (t < off) rq[t] += rq[t + off];
        __syncthreads();
    }
    if (t == 0) inv[r] = rsqrtf(rq[0]);
}

// ---------------- init / adjusted-prompt copy (x stays fp32), float4 ----------------
__global__ __launch_bounds__(256) void adjust_kernel(
    const float4* __restrict__ raw, const float* __restrict__ attr,
    float4* __restrict__ x, int total4)
{
    int i = blockIdx.x * 256 + threadIdx.x;
    if (i >= total4) return;
    int row = i >> 7;            // 128 float4 per row
    int l = row % LSEQ, n = row / LSEQ;
    float4 v = raw[i];
    if (attr != nullptr && l < PFX) {
        float sc = attr[n * PFX + l];
        v.x *= sc; v.y *= sc; v.z *= sc; v.w *= sc;
    }
    x[i] = v;
}

// ---------------- fused attention: block = one class n ----------------
__global__ __launch_bounds__(256) void attn_fused(
    const __hip_bfloat16* __restrict__ qkv,   // [n*12 + qi][1536]
    __hip_bfloat16* __restrict__ out,         // [n*12 + qi][512]
    float* __restrict__ plast)                // [n][8][12]
{
    const int n = blockIdx.x, t = threadIdx.x;
    __shared__ __hip_bfloat16 S[12][1544];    // cols: 0-511 Q, 512-1023 K, 1024-1535 V
    __shared__ float P[8][12][13];

    const __hip_bfloat16* src = qkv + (size_t)n * LSEQ * (3 * DMOD);
    for (int c = t; c < 12 * 192; c += 256) {
        int r = c / 192, col = (c % 192) * 8;
        *reinterpret_cast<bf16x8*>(&S[r][col]) =
            *reinterpret_cast<const bf16x8*>(&src[(size_t)r * (3 * DMOD) + col]);
    }
    __syncthreads();

    const int h = t >> 5, l32 = t & 31;
    if (l32 < LSEQ) {
        const int qi = l32;
        float sc[LSEQ];
        #pragma unroll
        for (int ki = 0; ki < LSEQ; ki++) {
            float acc = 0.f;
            #pragma unroll
            for (int d = 0; d < DHEAD; d += 8) {
                bf16x8 qv = *reinterpret_cast<const bf16x8*>(&S[qi][h * 64 + d]);
                bf16x8 kv = *reinterpret_cast<const bf16x8*>(&S[ki][512 + h * 64 + d]);
                #pragma unroll
                for (int e = 0; e < 8; e++)
                    acc += bf2f((unsigned short)qv[e]) * bf2f((unsigned short)kv[e]);
            }
            sc[ki] = acc * 0.125f + (ki > qi ? -1e9f : 0.f);
        }
        float m = sc[0];
        #pragma unroll
        for (int ki = 1; ki < LSEQ; ki++) m = fmaxf(m, sc[ki]);
        float e[LSEQ], s = 0.f;
        #pragma unroll
        for (int ki = 0; ki < LSEQ; ki++) { e[ki] = expf(sc[ki] - m); s += e[ki]; }
        float rcp = 1.0f / s;
        #pragma unroll
        for (int ki = 0; ki < LSEQ; ki++) P[h][qi][ki] = e[ki] * rcp;
        if (qi == LSEQ - 1) {
            #pragma unroll
            for (int ki = 0; ki < LSEQ; ki++)
                plast[((size_t)n * NHEAD + h) * LSEQ + ki] = e[ki] * rcp;
        }
    }
    __syncthreads();

    #pragma unroll
    for (int dd = 0; dd < 2; dd++) {
        int d = l32 * 2 + dd;
        for (int qi = 0; qi < LSEQ; qi++) {
            float acc = 0.f;
            #pragma unroll
            for (int ki = 0; ki < LSEQ; ki++)
                acc += P[h][qi][ki] * bf2f(((const unsigned short*)&S[ki][1024 + h * 64])[d]);
            out[((size_t)(n * LSEQ + qi)) * DMOD + h * 64 + d] = __float2bfloat16(acc);
        }
    }
}

// ---------------- attr from plast ----------------
__global__ __launch_bounds__(256) void attr_kernel(
    const float* __restrict__ plast, float* __restrict__ attr)
{
    int n = blockIdx.x * 256 + threadIdx.x;
    if (n >= NCLS) return;
    float a[PFX]; float s = 0.f;
    #pragma unroll
    for (int p = 0; p < PFX; p++) {
        float acc = 0.f;
        for (int hh = 0; hh < NHEAD; hh++)
            acc += plast[((size_t)n * NHEAD + hh) * LSEQ + p];
        a[p] = acc * (1.0f / NHEAD);
        s += a[p];
    }
    #pragma unroll
    for (int p = 0; p < PFX; p++) attr[n * PFX + p] = a[p] / (s + 1e-8f);
}

// ---------------- final prep ----------------
__global__ __launch_bounds__(256) void finalize_prep(
    const float* __restrict__ x, const float* __restrict__ images,
    __hip_bfloat16* __restrict__ xlast,   // [1024][512]
    __hip_bfloat16* __restrict__ img_bf,  // [256][512]
    __hip_bfloat16* __restrict__ tf_bf)   // [1024][512] (zero pad rows 1000..1023)
{
    int idx = blockIdx.x * 256 + threadIdx.x;
    const int NX = 1024 * DMOD, NI = BIMG * DMOD, NP = 24 * DMOD;
    if (idx < NX) {
        int r = idx >> 9, d = idx & 511;
        xlast[idx] = (r < NCLS) ? __float2bfloat16(x[((size_t)r * LSEQ + (LSEQ - 1)) * DMOD + d])
                                : __float2bfloat16(0.f);
    } else if (idx < NX + NI) {
        int j = idx - NX;
        img_bf[j] = __float2bfloat16(images[j]);
    } else if (idx < NX + NI + NP) {
        int j = idx - NX - NI;
        tf_bf[(size_t)NCLS * DMOD + j] = __float2bfloat16(0.f);
    }
}

// ---------------- attribution output ----------------
__global__ __launch_bounds__(256) void attribution_kernel(
    const float* __restrict__ attr, float* __restrict__ out2)
{
    int p = blockIdx.x, t = threadIdx.x;
    float s = 0.f;
    for (int n = t; n < NCLS; n += 256) s += attr[n * PFX + p];
    __shared__ float rq[256];
    rq[t] = s; __syncthreads();
    for (int off = 128; off > 0; off >>= 1) {
        if (t < off) rq[t] += rq[t + off];
        __syncthreads();
    }
    float mean = rq[0] * (1.0f / NCLS);
    out2[t * PFX + p] = mean;
}

extern "C" void kernel_launch(void* const* d_in, const int* in_sizes, int n_in,
                              void* d_out, int out_size, void* d_ws, size_t ws_size,
                              hipStream_t stream)
{
    const float* images = (const float*)d_in[0];
    const float* raw    = (const float*)d_in[1];
    const float* Wqkv   = (const float*)d_in[2];
    const float* bqkv   = (const float*)d_in[3];
    const float* Wo     = (const float*)d_in[4];
    const float* bo     = (const float*)d_in[5];
    const float* W1     = (const float*)d_in[6];
    const float* b1     = (const float*)d_in[7];
    const float* W2     = (const float*)d_in[8];
    const float* b2     = (const float*)d_in[9];
    const float* g1     = (const float*)d_in[10];
    const float* c1     = (const float*)d_in[11];
    const float* g2     = (const float*)d_in[12];
    const float* c2v    = (const float*)d_in[13];
    const float* tproj  = (const float*)d_in[14];
    const float* lsp    = (const float*)d_in[15];
    float* out = (float*)d_out;

    const int ROWS  = NCLS * LSEQ;   // 12000
    const int ROWSP = 12032;         // padded to 128-multiple

    float* ws    = (float*)d_ws;
    float* x     = ws;                                     // 12000*512
    float* plast = x + (size_t)ROWS * DMOD;                // 1000*8*12
    float* attr  = plast + (size_t)NCLS * NHEAD * LSEQ;    // 5120 (padded)
    float* invi  = attr + 5120;                            // 512
    float* invt  = invi + 512;                             // 1024
    __hip_bfloat16* h_bf   = (__hip_bfloat16*)(invt + 1024);        // 12032*512
    __hip_bfloat16* u_bf   = h_bf + (size_t)ROWSP * DMOD;           // 12032*2048
    __hip_bfloat16* wT     = u_bf + (size_t)ROWSP * DFF;
    const size_t LS = (size_t)(3 * DMOD) * DMOD + (size_t)DMOD * DMOD
                    + (size_t)DMOD * DFF + (size_t)DFF * DMOD;
    __hip_bfloat16* tprojT = wT + NLAY * LS;                        // 512*512
    __hip_bfloat16* xlast  = tprojT + (size_t)DMOD * DMOD;          // 1024*512
    __hip_bfloat16* img_bf = xlast + (size_t)1024 * DMOD;           // 256*512
    __hip_bfloat16* tf_bf  = img_bf + (size_t)BIMG * DMOD;          // 1024*512

    for (int l = 0; l < NLAY; l++) {
        __hip_bfloat16* wqkvT = wT + l * LS;
        __hip_bfloat16* woT   = wqkvT + (size_t)(3 * DMOD) * DMOD;
        __hip_bfloat16* w1T   = woT + (size_t)DMOD * DMOD;
        __hip_bfloat16* w2T   = w1T + (size_t)DMOD * DFF;
        transposeW<<<dim3(3 * DMOD / 32, DMOD / 32), 256, 0, stream>>>(
            Wqkv + (size_t)l * DMOD * 3 * DMOD, DMOD, 3 * DMOD, wqkvT);
        transposeW<<<dim3(DMOD / 32, DMOD / 32), 256, 0, stream>>>(
            Wo + (size_t)l * DMOD * DMOD, DMOD, DMOD, woT);
        transposeW<<<dim3(DFF / 32, DMOD / 32), 256, 0, stream>>>(
            W1 + (size_t)l * DMOD * DFF, DMOD, DFF, w1T);
        transposeW<<<dim3(DMOD / 32, DFF / 32), 256, 0, stream>>>(
            W2 + (size_t)l * DFF * DMOD, DFF, DMOD, w2T);
    }
    transposeW<<<dim3(DMOD / 32, DMOD / 32), 256, 0, stream>>>(tproj, DMOD, DMOD, tprojT);

    auto run_pass = [&](bool useAttr) {
        {
            int total4 = ROWS * DMOD / 4;
            adjust_kernel<<<(total4 + 255) / 256, 256, 0, stream>>>(
                (const float4*)raw, useAttr ? attr : nullptr, (float4*)x, total4);
        }
        for (int l = 0; l < NLAY; l++) {
            __hip_bfloat16* wqkvT = wT + l * LS;
            __hip_bfloat16* woT   = wqkvT + (size_t)(3 * DMOD) * DMOD;
            __hip_bfloat16* w1T   = woT + (size_t)DMOD * DMOD;
            __hip_bfloat16* w2T   = w1T + (size_t)DMOD * DFF;

            ln_bf16<<<ROWS / 4, 256, 0, stream>>>(x, g1 + l * DMOD, c1 + l * DMOD, h_bf);
            gemm_mfma<0><<<dim3(12, 94), 256, 0, stream>>>(
                h_bf, DMOD, wqkvT, DMOD, bqkv + l * 3 * DMOD,
                nullptr, 0, nullptr, 0, u_bf, 3 * DMOD, ROWS, DMOD,
                3 * DMOD, nullptr, nullptr, nullptr);
            attn_fused<<<NCLS, 256, 0, stream>>>(u_bf, h_bf, plast);
            gemm_mfma<2><<<dim3(4, 94), 256, 0, stream>>>(
                h_bf, DMOD, woT, DMOD, bo + l * DMOD,
                x, DMOD, x, DMOD, nullptr, 0, ROWS, DMOD,
                DMOD, nullptr, nullptr, nullptr);
            ln_bf16<<<ROWS / 4, 256, 0, stream>>>(x, g2 + l * DMOD, c2v + l * DMOD, h_bf);
            gemm_mfma<1><<<dim3(16, 94), 256, 0, stream>>>(
                h_bf, DMOD, w1T, DMOD, b1 + l * DFF,
                nullptr, 0, nullptr, 0, u_bf, DFF, ROWS, DMOD,
                DFF, nullptr, nullptr, nullptr);
            gemm_mfma<2><<<dim3(4, 94), 256, 0, stream>>>(
                u_bf, DFF, w2T, DFF, b2 + l * DMOD,
                x, DMOD, x, DMOD, nullptr, 0, ROWS, DFF,
                DMOD, nullptr, nullptr, nullptr);
        }
    };

    run_pass(false);
    attr_kernel<<<4, 256, 0, stream>>>(plast, attr);
    run_pass(true);

    {
        int total = 1024 * DMOD + BIMG * DMOD + 24 * DMOD;
        finalize_prep<<<(total + 255) / 256, 256, 0, stream>>>(x, images, xlast, img_bf, tf_bf);
    }
    gemm_mfma<0><<<dim3(4, 8), 256, 0, stream>>>(
        xlast, DMOD, tprojT, DMOD, nullptr,
        nullptr, 0, nullptr, 0, tf_bf, DMOD, NCLS, DMOD,
        DMOD, nullptr, nullptr, nullptr);
    rownorm_inv_bf16<<<NCLS, 256, 0, stream>>>(tf_bf, invt);
    rownorm_inv<<<BIMG, 256, 0, stream>>>(images, invi);
    gemm_mfma<3><<<dim3(8, 2), 256, 0, stream>>>(
        img_bf, DMOD, tf_bf, DMOD, nullptr,
        nullptr, 0, out, NCLS, nullptr, 0, BIMG, DMOD,
        NCLS, invi, invt, lsp);
    attribution_kernel<<<PFX, 256, 0, stream>>>(attr, out + (size_t)BIMG * NCLS);
}

// Round 5
// 1073.131 us; speedup vs baseline: 1.0755x; 1.0755x over previous
//
#include <hip/hip_runtime.h>
#include <hip/hip_bf16.h>

#define NCLS 1000
#define BIMG 256
#define LSEQ 12
#define PFX  5
#define DMOD 512
#define NHEAD 8
#define NLAY 2
#define DFF  2048
#define DHEAD 64

typedef __attribute__((ext_vector_type(8))) short bf16x8;
typedef __attribute__((ext_vector_type(4))) float f32x4;

__device__ __forceinline__ float gelu_tanh(float x) {
    const float c = 0.7978845608028654f;
    float t = tanhf(c * (x + 0.044715f * x * x * x));
    return 0.5f * x * (1.0f + t);
}

__device__ __forceinline__ float bf2f(unsigned short u) {
    unsigned int x = ((unsigned int)u) << 16;
    float f; __builtin_memcpy(&f, &x, 4); return f;
}

__device__ __forceinline__ short f2bf_s(float f) {
    __hip_bfloat16 h = __float2bfloat16(f);
    short s; __builtin_memcpy(&s, &h, 2); return s;
}

__device__ __forceinline__ void gload_lds16(const void* g, void* l) {
    __builtin_amdgcn_global_load_lds(
        (const __attribute__((address_space(1))) void*)g,
        (__attribute__((address_space(3))) void*)l, 16, 0, 0);
}

// ---------------- bf16 MFMA GEMM: m97 structure, 2-buffer, XCD swizzle, TN in {128,64} ----
// C = A(MxK bf16, row-major) @ B (supplied as Bt = N x K bf16 row-major)
// TN=128: 4 waves 2x2, each 64x64 (4x4 frags). TN=64: 4 waves stacked on M, each 32x64 (2x4 frags).
// EPI: 0=+bias->bf16 ; 1=+bias,gelu->bf16 ; 2=+bias,+R->f32 ; 3=exp(ls)*sM*sN->f32 (gn<Nreal guard)
template <int EPI, int TN>
__global__ __launch_bounds__(256) void gemm_mfma(
    const __hip_bfloat16* __restrict__ A, int lda,
    const __hip_bfloat16* __restrict__ Bt, int ldb,
    const float* __restrict__ bias,
    const float* __restrict__ R, int ldr,
    float* __restrict__ Cf, int ldcf,
    __hip_bfloat16* __restrict__ Cb, int ldcb,
    int M, int K, int Nreal,
    const float* __restrict__ scaleM,
    const float* __restrict__ scaleN,
    const float* __restrict__ lsp)
{
    constexpr int MI = (TN == 128) ? 4 : 2;
    __shared__ unsigned short As[2][128 * 32];
    __shared__ unsigned short Bs[2][TN * 32];
    const int t    = threadIdx.x;
    const int wid  = t >> 6, lane = t & 63;
    const int lr   = lane & 15, lk = lane >> 4;
    const int rb   = (TN == 128) ? (wid >> 1) * 64 : wid * 32;   // wave row base
    const int cb   = (TN == 128) ? (wid & 1) * 64 : 0;           // wave col base

    // bijective XCD swizzle (m204): consecutive same-XCD blocks share bn -> B-panel L2 reuse
    const unsigned int gx = gridDim.x, gy = gridDim.y;
    const unsigned int nwg = gx * gy;
    const unsigned int orig = blockIdx.y * gx + blockIdx.x;
    const unsigned int q8 = nwg >> 3, r8 = nwg & 7;
    const unsigned int xcd = orig & 7, slot = orig >> 3;
    const unsigned int wgid = (xcd < r8 ? xcd * (q8 + 1) : r8 * (q8 + 1) + (xcd - r8) * q8) + slot;
    const int bn = (int)(wgid / gy) * TN;
    const int bm = (int)(wgid % gy) * 128;

    const int srow   = t >> 2;        // 0..63 staging row
    const int schunk = (t & 3) * 8;   // element offset within BK=32

    f32x4 acc[MI][4] = {};

    const __hip_bfloat16* Abase = A  + (size_t)bm * lda;
    const __hip_bfloat16* Bbase = Bt + (size_t)bn * ldb;

    auto STAGE = [&](int k0, int buf) {
        char* ab = (char*)&As[buf][0];
        char* bb = (char*)&Bs[buf][0];
        gload_lds16(Abase + (size_t)srow        * lda + k0 + schunk, ab + wid * 1024);
        gload_lds16(Abase + (size_t)(srow + 64) * lda + k0 + schunk, ab + 4096 + wid * 1024);
        gload_lds16(Bbase + (size_t)srow        * ldb + k0 + schunk, bb + wid * 1024);
        if constexpr (TN == 128)
            gload_lds16(Bbase + (size_t)(srow + 64) * ldb + k0 + schunk, bb + 4096 + wid * 1024);
    };

    const int NIT = K >> 5;
    STAGE(0, 0);
    asm volatile("s_waitcnt vmcnt(0)" ::: "memory");
    __builtin_amdgcn_s_barrier();

    int cur = 0;
    for (int it = 0; it < NIT; it++) {
        if (it + 1 < NIT) STAGE((it + 1) << 5, cur ^ 1);   // prefetch next tile over MFMA

        bf16x8 a[MI], b[4];
        #pragma unroll
        for (int i = 0; i < MI; i++)
            a[i] = *reinterpret_cast<const bf16x8*>(&As[cur][(rb + i * 16 + lr) * 32 + lk * 8]);
        #pragma unroll
        for (int j = 0; j < 4; j++)
            b[j] = *reinterpret_cast<const bf16x8*>(&Bs[cur][(cb + j * 16 + lr) * 32 + lk * 8]);
        #pragma unroll
        for (int i = 0; i < MI; i++)
            #pragma unroll
            for (int j = 0; j < 4; j++)
                acc[i][j] = __builtin_amdgcn_mfma_f32_16x16x32_bf16(a[i], b[j], acc[i][j], 0, 0, 0);

        asm volatile("s_waitcnt vmcnt(0)" ::: "memory");
        __builtin_amdgcn_s_barrier();
        cur ^= 1;
    }

    // C/D layout (m89-verified): col = lane&15, row = (lane>>4)*4 + reg
    const float lsv = (EPI == 3) ? expf(lsp[0]) : 0.f;
    #pragma unroll
    for (int i = 0; i < MI; i++) {
        int gm0 = bm + rb + i * 16 + lk * 4;
        #pragma unroll
        for (int j = 0; j < 4; j++) {
            int gn = bn + cb + j * 16 + lr;
            float bv = (EPI <= 2 && bias) ? bias[gn] : 0.f;
            #pragma unroll
            for (int q = 0; q < 4; q++) {
                int gm = gm0 + q;
                if (gm >= M) continue;
                float v = acc[i][j][q] + bv;
                if (EPI == 1) v = gelu_tanh(v);
                if (EPI == 2) {
                    Cf[(size_t)gm * ldcf + gn] = v + R[(size_t)gm * ldr + gn];
                } else if (EPI == 3) {
                    if (gn < Nreal)
                        Cf[(size_t)gm * ldcf + gn] = lsv * scaleM[gm] * scaleN[gn] * acc[i][j][q];
                } else {
                    Cb[(size_t)gm * ldcb + gn] = __float2bfloat16(v);
                }
            }
        }
    }
}

// ---------------- weight transpose + f32->bf16 ----------------
__global__ __launch_bounds__(256) void transposeW(
    const float* __restrict__ W, int rows, int cols, __hip_bfloat16* __restrict__ Wt)
{
    __shared__ float tile[32][33];
    int bc = blockIdx.x * 32;
    int br = blockIdx.y * 32;
    int tx = threadIdx.x & 31, ty = threadIdx.x >> 5;
    #pragma unroll
    for (int i = 0; i < 4; i++) {
        int r = ty + i * 8;
        tile[r][tx] = W[(size_t)(br + r) * cols + bc + tx];
    }
    __syncthreads();
    #pragma unroll
    for (int i = 0; i < 4; i++) {
        int r = ty + i * 8;
        Wt[(size_t)(bc + r) * rows + br + tx] = __float2bfloat16(tile[tx][r]);
    }
}

// ---------------- LayerNorm: wave-per-row (4 rows/block) ----------------
__global__ __launch_bounds__(256) void ln_bf16(
    const float* __restrict__ x, const float* __restrict__ g,
    const float* __restrict__ b, __hip_bfloat16* __restrict__ o)
{
    const int lane = threadIdx.x & 63;
    const int r = blockIdx.x * 4 + (threadIdx.x >> 6);
    const float4* xr = (const float4*)(x + (size_t)r * DMOD);
    float4 u = xr[lane * 2], v = xr[lane * 2 + 1];
    float s  = u.x + u.y + u.z + u.w + v.x + v.y + v.z + v.w;
    float qq = u.x*u.x + u.y*u.y + u.z*u.z + u.w*u.w
             + v.x*v.x + v.y*v.y + v.z*v.z + v.w*v.w;
    #pragma unroll
    for (int off = 32; off > 0; off >>= 1) {
        s  += __shfl_xor(s,  off, 64);
        qq += __shfl_xor(qq, off, 64);
    }
    float mean = s * (1.0f / DMOD);
    float inv  = rsqrtf(qq * (1.0f / DMOD) - mean * mean + 1e-5f);
    const float4* g4 = (const float4*)g;
    const float4* b4 = (const float4*)b;
    float4 ga = g4[lane * 2], gb = g4[lane * 2 + 1];
    float4 ba = b4[lane * 2], bb = b4[lane * 2 + 1];
    bf16x8 o8;
    o8[0] = f2bf_s((u.x - mean) * inv * ga.x + ba.x);
    o8[1] = f2bf_s((u.y - mean) * inv * ga.y + ba.y);
    o8[2] = f2bf_s((u.z - mean) * inv * ga.z + ba.z);
    o8[3] = f2bf_s((u.w - mean) * inv * ga.w + ba.w);
    o8[4] = f2bf_s((v.x - mean) * inv * gb.x + bb.x);
    o8[5] = f2bf_s((v.y - mean) * inv * gb.y + bb.y);
    o8[6] = f2bf_s((v.z - mean) * inv * gb.z + bb.z);
    o8[7] = f2bf_s((v.w - mean) * inv * gb.w + bb.w);
    *reinterpret_cast<bf16x8*>(&o[(size_t)r * DMOD + lane * 8]) = o8;
}

// ---------------- fused adjust (raw * attr-scale) + write x + LN -> bf16 ----------------
__global__ __launch_bounds__(256) void adjust_ln(
    const float* __restrict__ raw, const float* __restrict__ attr,
    const float* __restrict__ g, const float* __restrict__ b,
    float* __restrict__ x, __hip_bfloat16* __restrict__ o)
{
    const int lane = threadIdx.x & 63;
    const int r = blockIdx.x * 4 + (threadIdx.x >> 6);
    const int l = r % LSEQ, n = r / LSEQ;
    const float sc = (l < PFX) ? attr[n * PFX + l] : 1.0f;
    const float4* xr = (const float4*)(raw + (size_t)r * DMOD);
    float4 u = xr[lane * 2], v = xr[lane * 2 + 1];
    u.x *= sc; u.y *= sc; u.z *= sc; u.w *= sc;
    v.x *= sc; v.y *= sc; v.z *= sc; v.w *= sc;
    float4* xo = (float4*)(x + (size_t)r * DMOD);
    xo[lane * 2] = u; xo[lane * 2 + 1] = v;
    float s  = u.x + u.y + u.z + u.w + v.x + v.y + v.z + v.w;
    float qq = u.x*u.x + u.y*u.y + u.z*u.z + u.w*u.w
             + v.x*v.x + v.y*v.y + v.z*v.z + v.w*v.w;
    #pragma unroll
    for (int off = 32; off > 0; off >>= 1) {
        s  += __shfl_xor(s,  off, 64);
        qq += __shfl_xor(qq, off, 64);
    }
    float mean = s * (1.0f / DMOD);
    float inv  = rsqrtf(qq * (1.0f / DMOD) - mean * mean + 1e-5f);
    const float4* g4 = (const float4*)g;
    const float4* b4 = (const float4*)b;
    float4 ga = g4[lane * 2], gb = g4[lane * 2 + 1];
    float4 ba = b4[lane * 2], bb = b4[lane * 2 + 1];
    bf16x8 o8;
    o8[0] = f2bf_s((u.x - mean) * inv * ga.x + ba.x);
    o8[1] = f2bf_s((u.y - mean) * inv * ga.y + ba.y);
    o8[2] = f2bf_s((u.z - mean) * inv * ga.z + ba.z);
    o8[3] = f2bf_s((u.w - mean) * inv * ga.w + ba.w);
    o8[4] = f2bf_s((v.x - mean) * inv * gb.x + bb.x);
    o8[5] = f2bf_s((v.y - mean) * inv * gb.y + bb.y);
    o8[6] = f2bf_s((v.z - mean) * inv * gb.z + bb.z);
    o8[7] = f2bf_s((v.w - mean) * inv * gb.w + bb.w);
    *reinterpret_cast<bf16x8*>(&o[(size_t)r * DMOD + lane * 8]) = o8;
}

// ---------------- inverse L2 row norm, fp32 input ----------------
__global__ __launch_bounds__(256) void rownorm_inv(
    const float* __restrict__ x, float* __restrict__ inv)
{
    const int r = blockIdx.x, t = threadIdx.x;
    const float* xr = x + (size_t)r * DMOD;
    float v0 = xr[t], v1 = xr[t + 256];
    __shared__ float rq[256];
    rq[t] = v0 * v0 + v1 * v1;
    __syncthreads();
    for (int off = 128; off > 0; off >>= 1) {
        if (t < off) rq[t] += rq[t + off];
        __syncthreads();
    }
    if (t == 0) inv[r] = rsqrtf(rq[0]);
}

// ---------------- inverse L2 row norm, bf16 input ----------------
__global__ __launch_bounds__(256) void rownorm_inv_bf16(
    const __hip_bfloat16* __restrict__ x, float* __restrict__ inv)
{
    const int r = blockIdx.x, t = threadIdx.x;
    const unsigned short* xr = (const unsigned short*)(x + (size_t)r * DMOD);
    float v0 = bf2f(xr[t]), v1 = bf2f(xr[t + 256]);
    __shared__ float rq[256];
    rq[t] = v0 * v0 + v1 * v1;
    __syncthreads();
    for (int off = 128; off > 0; off >>= 1) {
        if (t < off) rq[t] += rq[t + off];
        __syncthreads();
    }
    if (t == 0) inv[r] = rsqrtf(rq[0]);
}

// ---------------- fused attention: block = one class n ----------------
__global__ __launch_bounds__(256) void attn_fused(
    const __hip_bfloat16* __restrict__ qkv,   // [n*12 + qi][1536]
    __hip_bfloat16* __restrict__ out,         // [n*12 + qi][512]
    float* __restrict__ plast)                // [n][8][12]
{
    const int n = blockIdx.x, t = threadIdx.x;
    __shared__ __hip_bfloat16 S[12][1544];    // cols: 0-511 Q, 512-1023 K, 1024-1535 V
    __shared__ float P[8][12][13];

    const __hip_bfloat16* src = qkv + (size_t)n * LSEQ * (3 * DMOD);
    for (int c = t; c < 12 * 192; c += 256) {
        int r = c / 192, col = (c % 192) * 8;
        *reinterpret_cast<bf16x8*>(&S[r][col]) =
            *reinterpret_cast<const bf16x8*>(&src[(size_t)r * (3 * DMOD) + col]);
    }
    __syncthreads();

    const int h = t >> 5, l32 = t & 31;
    if (l32 < LSEQ) {
        const int qi = l32;
        float sc[LSEQ];
        #pragma unroll
        for (int ki = 0; ki < LSEQ; ki++) {
            float acc = 0.f;
            #pragma unroll
            for (int d = 0; d < DHEAD; d += 8) {
                bf16x8 qv = *reinterpret_cast<const bf16x8*>(&S[qi][h * 64 + d]);
                bf16x8 kv = *reinterpret_cast<const bf16x8*>(&S[ki][512 + h * 64 + d]);
                #pragma unroll
                for (int e = 0; e < 8; e++)
                    acc += bf2f((unsigned short)qv[e]) * bf2f((unsigned short)kv[e]);
            }
            sc[ki] = acc * 0.125f + (ki > qi ? -1e9f : 0.f);
        }
        float m = sc[0];
        #pragma unroll
        for (int ki = 1; ki < LSEQ; ki++) m = fmaxf(m, sc[ki]);
        float e[LSEQ], s = 0.f;
        #pragma unroll
        for (int ki = 0; ki < LSEQ; ki++) { e[ki] = expf(sc[ki] - m); s += e[ki]; }
        float rcp = 1.0f / s;
        #pragma unroll
        for (int ki = 0; ki < LSEQ; ki++) P[h][qi][ki] = e[ki] * rcp;
        if (qi == LSEQ - 1) {
            #pragma unroll
            for (int ki = 0; ki < LSEQ; ki++)
                plast[((size_t)n * NHEAD + h) * LSEQ + ki] = e[ki] * rcp;
        }
    }
    __syncthreads();

    #pragma unroll
    for (int dd = 0; dd < 2; dd++) {
        int d = l32 * 2 + dd;
        for (int qi = 0; qi < LSEQ; qi++) {
            float acc = 0.f;
            #pragma unroll
            for (int ki = 0; ki < LSEQ; ki++)
                acc += P[h][qi][ki] * bf2f(((const unsigned short*)&S[ki][1024 + h * 64])[d]);
            out[((size_t)(n * LSEQ + qi)) * DMOD + h * 64 + d] = __float2bfloat16(acc);
        }
    }
}

// ---------------- attr from plast ----------------
__global__ __launch_bounds__(256) void attr_kernel(
    const float* __restrict__ plast, float* __restrict__ attr)
{
    int n = blockIdx.x * 256 + threadIdx.x;
    if (n >= NCLS) return;
    float a[PFX]; float s = 0.f;
    #pragma unroll
    for (int p = 0; p < PFX; p++) {
        float acc = 0.f;
        for (int hh = 0; hh < NHEAD; hh++)
            acc += plast[((size_t)n * NHEAD + hh) * LSEQ + p];
        a[p] = acc * (1.0f / NHEAD);
        s += a[p];
    }
    #pragma unroll
    for (int p = 0; p < PFX; p++) attr[n * PFX + p] = a[p] / (s + 1e-8f);
}

// ---------------- final prep ----------------
__global__ __launch_bounds__(256) void finalize_prep(
    const float* __restrict__ x, const float* __restrict__ images,
    __hip_bfloat16* __restrict__ xlast,   // [1024][512]
    __hip_bfloat16* __restrict__ img_bf,  // [256][512]
    __hip_bfloat16* __restrict__ tf_bf)   // [1024][512] (zero pad rows 1000..1023)
{
    int idx = blockIdx.x * 256 + threadIdx.x;
    const int NX = 1024 * DMOD, NI = BIMG * DMOD, NP = 24 * DMOD;
    if (idx < NX) {
        int r = idx >> 9, d = idx & 511;
        xlast[idx] = (r < NCLS) ? __float2bfloat16(x[((size_t)r * LSEQ + (LSEQ - 1)) * DMOD + d])
                                : __float2bfloat16(0.f);
    } else if (idx < NX + NI) {
        int j = idx - NX;
        img_bf[j] = __float2bfloat16(images[j]);
    } else if (idx < NX + NI + NP) {
        int j = idx - NX - NI;
        tf_bf[(size_t)NCLS * DMOD + j] = __float2bfloat16(0.f);
    }
}

// ---------------- attribution output ----------------
__global__ __launch_bounds__(256) void attribution_kernel(
    const float* __restrict__ attr, float* __restrict__ out2)
{
    int p = blockIdx.x, t = threadIdx.x;
    float s = 0.f;
    for (int n = t; n < NCLS; n += 256) s += attr[n * PFX + p];
    __shared__ float rq[256];
    rq[t] = s; __syncthreads();
    for (int off = 128; off > 0; off >>= 1) {
        if (t < off) rq[t] += rq[t + off];
        __syncthreads();
    }
    float mean = rq[0] * (1.0f / NCLS);
    out2[t * PFX + p] = mean;
}

extern "C" void kernel_launch(void* const* d_in, const int* in_sizes, int n_in,
                              void* d_out, int out_size, void* d_ws, size_t ws_size,
                              hipStream_t stream)
{
    const float* images = (const float*)d_in[0];
    const float* raw    = (const float*)d_in[1];
    const float* Wqkv   = (const float*)d_in[2];
    const float* bqkv   = (const float*)d_in[3];
    const float* Wo     = (const float*)d_in[4];
    const float* bo     = (const float*)d_in[5];
    const float* W1     = (const float*)d_in[6];
    const float* b1     = (const float*)d_in[7];
    const float* W2     = (const float*)d_in[8];
    const float* b2     = (const float*)d_in[9];
    const float* g1     = (const float*)d_in[10];
    const float* c1     = (const float*)d_in[11];
    const float* g2     = (const float*)d_in[12];
    const float* c2v    = (const float*)d_in[13];
    const float* tproj  = (const float*)d_in[14];
    const float* lsp    = (const float*)d_in[15];
    float* out = (float*)d_out;

    const int ROWS  = NCLS * LSEQ;   // 12000
    const int ROWSP = 12032;         // padded to 128-multiple

    float* ws    = (float*)d_ws;
    float* x     = ws;                                     // 12000*512
    float* plast = x + (size_t)ROWS * DMOD;                // 1000*8*12
    float* attr  = plast + (size_t)NCLS * NHEAD * LSEQ;    // 5120 (padded)
    float* invi  = attr + 5120;                            // 512
    float* invt  = invi + 512;                             // 1024
    __hip_bfloat16* h_bf   = (__hip_bfloat16*)(invt + 1024);        // 12032*512
    __hip_bfloat16* u_bf   = h_bf + (size_t)ROWSP * DMOD;           // 12032*2048
    __hip_bfloat16* wT     = u_bf + (size_t)ROWSP * DFF;
    const size_t LS = (size_t)(3 * DMOD) * DMOD + (size_t)DMOD * DMOD
                    + (size_t)DMOD * DFF + (size_t)DFF * DMOD;
    __hip_bfloat16* tprojT = wT + NLAY * LS;                        // 512*512
    __hip_bfloat16* xlast  = tprojT + (size_t)DMOD * DMOD;          // 1024*512
    __hip_bfloat16* img_bf = xlast + (size_t)1024 * DMOD;           // 256*512
    __hip_bfloat16* tf_bf  = img_bf + (size_t)BIMG * DMOD;          // 1024*512

    for (int l = 0; l < NLAY; l++) {
        __hip_bfloat16* wqkvT = wT + l * LS;
        __hip_bfloat16* woT   = wqkvT + (size_t)(3 * DMOD) * DMOD;
        __hip_bfloat16* w1T   = woT + (size_t)DMOD * DMOD;
        __hip_bfloat16* w2T   = w1T + (size_t)DMOD * DFF;
        transposeW<<<dim3(3 * DMOD / 32, DMOD / 32), 256, 0, stream>>>(
            Wqkv + (size_t)l * DMOD * 3 * DMOD, DMOD, 3 * DMOD, wqkvT);
        transposeW<<<dim3(DMOD / 32, DMOD / 32), 256, 0, stream>>>(
            Wo + (size_t)l * DMOD * DMOD, DMOD, DMOD, woT);
        transposeW<<<dim3(DFF / 32, DMOD / 32), 256, 0, stream>>>(
            W1 + (size_t)l * DMOD * DFF, DMOD, DFF, w1T);
        transposeW<<<dim3(DMOD / 32, DFF / 32), 256, 0, stream>>>(
            W2 + (size_t)l * DFF * DMOD, DFF, DMOD, w2T);
    }
    transposeW<<<dim3(DMOD / 32, DMOD / 32), 256, 0, stream>>>(tproj, DMOD, DMOD, tprojT);

    auto run_pass = [&](bool useAttr) {
        for (int l = 0; l < NLAY; l++) {
            __hip_bfloat16* wqkvT = wT + l * LS;
            __hip_bfloat16* woT   = wqkvT + (size_t)(3 * DMOD) * DMOD;
            __hip_bfloat16* w1T   = woT + (size_t)DMOD * DMOD;
            __hip_bfloat16* w2T   = w1T + (size_t)DMOD * DFF;

            // LN1 (layer 0: read raw directly; pass2 also materializes x = raw*attr)
            if (l == 0) {
                if (useAttr)
                    adjust_ln<<<ROWS / 4, 256, 0, stream>>>(raw, attr, g1, c1, x, h_bf);
                else
                    ln_bf16<<<ROWS / 4, 256, 0, stream>>>(raw, g1, c1, h_bf);
            } else {
                ln_bf16<<<ROWS / 4, 256, 0, stream>>>(x, g1 + l * DMOD, c1 + l * DMOD, h_bf);
            }
            // qkv = h @ Wqkv + bqkv (TN=128, grid 12x94)
            gemm_mfma<0, 128><<<dim3(12, 94), 256, 0, stream>>>(
                h_bf, DMOD, wqkvT, DMOD, bqkv + l * 3 * DMOD,
                nullptr, 0, nullptr, 0, u_bf, 3 * DMOD, ROWS, DMOD,
                3 * DMOD, nullptr, nullptr, nullptr);
            attn_fused<<<NCLS, 256, 0, stream>>>(u_bf, h_bf, plast);
            // x = R + attn_out @ Wo + bo  (layer0 pass1: R = raw, avoids materializing x)
            {
                const float* Rsrc = (l == 0 && !useAttr) ? raw : x;
                gemm_mfma<2, 64><<<dim3(8, 94), 256, 0, stream>>>(
                    h_bf, DMOD, woT, DMOD, bo + l * DMOD,
                    Rsrc, DMOD, x, DMOD, nullptr, 0, ROWS, DMOD,
                    DMOD, nullptr, nullptr, nullptr);
            }
            ln_bf16<<<ROWS / 4, 256, 0, stream>>>(x, g2 + l * DMOD, c2v + l * DMOD, h_bf);
            // g = gelu(h @ W1 + b1) (TN=128, grid 16x94)
            gemm_mfma<1, 128><<<dim3(16, 94), 256, 0, stream>>>(
                h_bf, DMOD, w1T, DMOD, b1 + l * DFF,
                nullptr, 0, nullptr, 0, u_bf, DFF, ROWS, DMOD,
                DFF, nullptr, nullptr, nullptr);
            // x = x + g @ W2 + b2 (TN=64, grid 8x94 = 752 blocks)
            gemm_mfma<2, 64><<<dim3(8, 94), 256, 0, stream>>>(
                u_bf, DFF, w2T, DFF, b2 + l * DMOD,
                x, DMOD, x, DMOD, nullptr, 0, ROWS, DFF,
                DMOD, nullptr, nullptr, nullptr);
        }
    };

    run_pass(false);
    attr_kernel<<<4, 256, 0, stream>>>(plast, attr);
    run_pass(true);

    {
        int total = 1024 * DMOD + BIMG * DMOD + 24 * DMOD;
        finalize_prep<<<(total + 255) / 256, 256, 0, stream>>>(x, images, xlast, img_bf, tf_bf);
    }
    gemm_mfma<0, 64><<<dim3(8, 8), 256, 0, stream>>>(
        xlast, DMOD, tprojT, DMOD, nullptr,
        nullptr, 0, nullptr, 0, tf_bf, DMOD, NCLS, DMOD,
        DMOD, nullptr, nullptr, nullptr);
    rownorm_inv_bf16<<<NCLS, 256, 0, stream>>>(tf_bf, invt);
    rownorm_inv<<<BIMG, 256, 0, stream>>>(images, invi);
    gemm_mfma<3, 64><<<dim3(16, 2), 256, 0, stream>>>(
        img_bf, DMOD, tf_bf, DMOD, nullptr,
        nullptr, 0, out, NCLS, nullptr, 0, BIMG, DMOD,
        NCLS, invi, invt, lsp);
    attribution_kernel<<<PFX, 256, 0, stream>>>(attr, out + (size_t)BIMG * NCLS);
}

// Round 6
// 1009.522 us; speedup vs baseline: 1.1433x; 1.0630x over previous
//
#include <hip/hip_runtime.h>
#include <hip/hip_bf16.h>

#define NCLS 1000
#define BIMG 256
#define LSEQ 12
#define PFX  5
#define DMOD 512
#define NHEAD 8
#define NLAY 2
#define DFF  2048
#define DHEAD 64

typedef __attribute__((ext_vector_type(8))) short bf16x8;
typedef __attribute__((ext_vector_type(4))) float f32x4;

__device__ __forceinline__ float gelu_tanh(float x) {
    const float c = 0.7978845608028654f;
    float t = tanhf(c * (x + 0.044715f * x * x * x));
    return 0.5f * x * (1.0f + t);
}

__device__ __forceinline__ float bf2f(unsigned short u) {
    unsigned int x = ((unsigned int)u) << 16;
    float f; __builtin_memcpy(&f, &x, 4); return f;
}

__device__ __forceinline__ short f2bf_s(float f) {
    __hip_bfloat16 h = __float2bfloat16(f);
    short s; __builtin_memcpy(&s, &h, 2); return s;
}

__device__ __forceinline__ void gload_lds16(const void* g, void* l) {
    __builtin_amdgcn_global_load_lds(
        (const __attribute__((address_space(1))) void*)g,
        (__attribute__((address_space(3))) void*)l, 16, 0, 0);
}

// ---------------- bf16 MFMA GEMM: 128x128, 2-buffer, XCD chunks with bn-FAST ordering ----
// C = A(MxK bf16, row-major) @ B (Bt = N x K bf16 row-major)
// EPI: 0=+bias->bf16 ; 1=+bias,gelu->bf16 ; 2=+bias,+Rb(bf16)->bf16 ; 3=exp(ls)*sM*sN->f32 (gn<Nreal)
template <int EPI>
__global__ __launch_bounds__(256) void gemm_mfma(
    const __hip_bfloat16* __restrict__ A, int lda,
    const __hip_bfloat16* __restrict__ Bt, int ldb,
    const float* __restrict__ bias,
    const __hip_bfloat16* __restrict__ Rb, int ldr,
    float* __restrict__ Cf, int ldcf,
    __hip_bfloat16* __restrict__ Cb, int ldcb,
    int M, int K, int Nreal,
    const float* __restrict__ scaleM,
    const float* __restrict__ scaleN,
    const float* __restrict__ lsp)
{
    __shared__ unsigned short As[2][128 * 32];
    __shared__ unsigned short Bs[2][128 * 32];
    const int t    = threadIdx.x;
    const int wid  = t >> 6, lane = t & 63;
    const int wm   = wid >> 1, wn = wid & 1;
    const int lr   = lane & 15, lk = lane >> 4;

    // m204 bijective XCD chunking; bn FAST within a chunk so an XCD's concurrent
    // blocks share the A m-panel (L2-hit) while B panels stay L2-resident.
    const unsigned int gx = gridDim.x, gy = gridDim.y;
    const unsigned int nwg = gx * gy;
    const unsigned int orig = blockIdx.y * gx + blockIdx.x;
    const unsigned int q8 = nwg >> 3, r8 = nwg & 7;
    const unsigned int xcd = orig & 7, slot = orig >> 3;
    const unsigned int wgid = (xcd < r8 ? xcd * (q8 + 1) : r8 * (q8 + 1) + (xcd - r8) * q8) + slot;
    const int bn = (int)(wgid % gx) * 128;
    const int bm = (int)(wgid / gx) * 128;

    const int srow   = t >> 2;        // 0..63 staging row
    const int schunk = (t & 3) * 8;   // element offset within BK=32

    f32x4 acc[4][4] = {};

    const __hip_bfloat16* Abase = A  + (size_t)bm * lda;
    const __hip_bfloat16* Bbase = Bt + (size_t)bn * ldb;

    auto STAGE = [&](int k0, int buf) {
        char* ab = (char*)&As[buf][0];
        char* bb = (char*)&Bs[buf][0];
        gload_lds16(Abase + (size_t)srow        * lda + k0 + schunk, ab + wid * 1024);
        gload_lds16(Abase + (size_t)(srow + 64) * lda + k0 + schunk, ab + 4096 + wid * 1024);
        gload_lds16(Bbase + (size_t)srow        * ldb + k0 + schunk, bb + wid * 1024);
        gload_lds16(Bbase + (size_t)(srow + 64) * ldb + k0 + schunk, bb + 4096 + wid * 1024);
    };

    const int NIT = K >> 5;
    STAGE(0, 0);
    asm volatile("s_waitcnt vmcnt(0)" ::: "memory");
    __builtin_amdgcn_s_barrier();

    int cur = 0;
    for (int it = 0; it < NIT; it++) {
        if (it + 1 < NIT) STAGE((it + 1) << 5, cur ^ 1);   // prefetch next tile over MFMA

        bf16x8 a[4], b[4];
        #pragma unroll
        for (int i = 0; i < 4; i++)
            a[i] = *reinterpret_cast<const bf16x8*>(&As[cur][(wm * 64 + i * 16 + lr) * 32 + lk * 8]);
        #pragma unroll
        for (int j = 0; j < 4; j++)
            b[j] = *reinterpret_cast<const bf16x8*>(&Bs[cur][(wn * 64 + j * 16 + lr) * 32 + lk * 8]);
        #pragma unroll
        for (int i = 0; i < 4; i++)
            #pragma unroll
            for (int j = 0; j < 4; j++)
                acc[i][j] = __builtin_amdgcn_mfma_f32_16x16x32_bf16(a[i], b[j], acc[i][j], 0, 0, 0);

        asm volatile("s_waitcnt vmcnt(0)" ::: "memory");
        __builtin_amdgcn_s_barrier();
        cur ^= 1;
    }

    // C/D layout (m89-verified): col = lane&15, row = (lane>>4)*4 + reg
    const float lsv = (EPI == 3) ? expf(lsp[0]) : 0.f;
    #pragma unroll
    for (int i = 0; i < 4; i++) {
        int gm0 = bm + wm * 64 + i * 16 + lk * 4;
        #pragma unroll
        for (int j = 0; j < 4; j++) {
            int gn = bn + wn * 64 + j * 16 + lr;
            float bv = (EPI <= 2 && bias) ? bias[gn] : 0.f;
            #pragma unroll
            for (int q = 0; q < 4; q++) {
                int gm = gm0 + q;
                if (gm >= M) continue;
                float v = acc[i][j][q] + bv;
                if (EPI == 1) v = gelu_tanh(v);
                if (EPI == 2) {
                    v += bf2f(((const unsigned short*)Rb)[(size_t)gm * ldr + gn]);
                    Cb[(size_t)gm * ldcb + gn] = __float2bfloat16(v);
                } else if (EPI == 3) {
                    if (gn < Nreal)
                        Cf[(size_t)gm * ldcf + gn] = lsv * scaleM[gm] * scaleN[gn] * acc[i][j][q];
                } else {
                    Cb[(size_t)gm * ldcb + gn] = __float2bfloat16(v);
                }
            }
        }
    }
}

// ---------------- weight transpose + f32->bf16 ----------------
__global__ __launch_bounds__(256) void transposeW(
    const float* __restrict__ W, int rows, int cols, __hip_bfloat16* __restrict__ Wt)
{
    __shared__ float tile[32][33];
    int bc = blockIdx.x * 32;
    int br = blockIdx.y * 32;
    int tx = threadIdx.x & 31, ty = threadIdx.x >> 5;
    #pragma unroll
    for (int i = 0; i < 4; i++) {
        int r = ty + i * 8;
        tile[r][tx] = W[(size_t)(br + r) * cols + bc + tx];
    }
    __syncthreads();
    #pragma unroll
    for (int i = 0; i < 4; i++) {
        int r = ty + i * 8;
        Wt[(size_t)(bc + r) * rows + br + tx] = __float2bfloat16(tile[tx][r]);
    }
}

// ---------------- LayerNorm, bf16 input (residual stream), wave-per-row ----------------
__global__ __launch_bounds__(256) void ln_b16(
    const __hip_bfloat16* __restrict__ x, const float* __restrict__ g,
    const float* __restrict__ b, __hip_bfloat16* __restrict__ o)
{
    const int lane = threadIdx.x & 63;
    const int r = blockIdx.x * 4 + (threadIdx.x >> 6);
    bf16x8 xv = *reinterpret_cast<const bf16x8*>(&x[(size_t)r * DMOD + lane * 8]);
    float f[8];
    #pragma unroll
    for (int e = 0; e < 8; e++) f[e] = bf2f((unsigned short)xv[e]);
    float s = 0.f, qq = 0.f;
    #pragma unroll
    for (int e = 0; e < 8; e++) { s += f[e]; qq += f[e] * f[e]; }
    #pragma unroll
    for (int off = 32; off > 0; off >>= 1) {
        s  += __shfl_xor(s,  off, 64);
        qq += __shfl_xor(qq, off, 64);
    }
    float mean = s * (1.0f / DMOD);
    float inv  = rsqrtf(qq * (1.0f / DMOD) - mean * mean + 1e-5f);
    const float4* g4 = (const float4*)g;
    const float4* b4 = (const float4*)b;
    float4 ga = g4[lane * 2], gb = g4[lane * 2 + 1];
    float4 ba = b4[lane * 2], bb = b4[lane * 2 + 1];
    float gg[8] = {ga.x, ga.y, ga.z, ga.w, gb.x, gb.y, gb.z, gb.w};
    float bbv[8] = {ba.x, ba.y, ba.z, ba.w, bb.x, bb.y, bb.z, bb.w};
    bf16x8 o8;
    #pragma unroll
    for (int e = 0; e < 8; e++) o8[e] = f2bf_s((f[e] - mean) * inv * gg[e] + bbv[e]);
    *reinterpret_cast<bf16x8*>(&o[(size_t)r * DMOD + lane * 8]) = o8;
}

// ---------------- fused (optional attr-scale) + write x(bf16) + LN -> bf16 ----------------
__global__ __launch_bounds__(256) void adjust_ln(
    const float* __restrict__ raw, const float* __restrict__ attr,
    const float* __restrict__ g, const float* __restrict__ b,
    __hip_bfloat16* __restrict__ x, __hip_bfloat16* __restrict__ o)
{
    const int lane = threadIdx.x & 63;
    const int r = blockIdx.x * 4 + (threadIdx.x >> 6);
    const int l = r % LSEQ, n = r / LSEQ;
    const float sc = (attr != nullptr && l < PFX) ? attr[n * PFX + l] : 1.0f;
    const float4* xr = (const float4*)(raw + (size_t)r * DMOD);
    float4 u = xr[lane * 2], v = xr[lane * 2 + 1];
    float f[8] = {u.x * sc, u.y * sc, u.z * sc, u.w * sc,
                  v.x * sc, v.y * sc, v.z * sc, v.w * sc};
    bf16x8 x8;
    #pragma unroll
    for (int e = 0; e < 8; e++) x8[e] = f2bf_s(f[e]);
    *reinterpret_cast<bf16x8*>(&x[(size_t)r * DMOD + lane * 8]) = x8;
    float s = 0.f, qq = 0.f;
    #pragma unroll
    for (int e = 0; e < 8; e++) { s += f[e]; qq += f[e] * f[e]; }
    #pragma unroll
    for (int off = 32; off > 0; off >>= 1) {
        s  += __shfl_xor(s,  off, 64);
        qq += __shfl_xor(qq, off, 64);
    }
    float mean = s * (1.0f / DMOD);
    float inv  = rsqrtf(qq * (1.0f / DMOD) - mean * mean + 1e-5f);
    const float4* g4 = (const float4*)g;
    const float4* b4 = (const float4*)b;
    float4 ga = g4[lane * 2], gb = g4[lane * 2 + 1];
    float4 ba = b4[lane * 2], bb = b4[lane * 2 + 1];
    float gg[8] = {ga.x, ga.y, ga.z, ga.w, gb.x, gb.y, gb.z, gb.w};
    float bbv[8] = {ba.x, ba.y, ba.z, ba.w, bb.x, bb.y, bb.z, bb.w};
    bf16x8 o8;
    #pragma unroll
    for (int e = 0; e < 8; e++) o8[e] = f2bf_s((f[e] - mean) * inv * gg[e] + bbv[e]);
    *reinterpret_cast<bf16x8*>(&o[(size_t)r * DMOD + lane * 8]) = o8;
}

// ---------------- inverse L2 row norm, fp32 input ----------------
__global__ __launch_bounds__(256) void rownorm_inv(
    const float* __restrict__ x, float* __restrict__ inv)
{
    const int r = blockIdx.x, t = threadIdx.x;
    const float* xr = x + (size_t)r * DMOD;
    float v0 = xr[t], v1 = xr[t + 256];
    __shared__ float rq[256];
    rq[t] = v0 * v0 + v1 * v1;
    __syncthreads();
    for (int off = 128; off > 0; off >>= 1) {
        if (t < off) rq[t] += rq[t + off];
        __syncthreads();
    }
    if (t == 0) inv[r] = rsqrtf(rq[0]);
}

// ---------------- inverse L2 row norm, bf16 input ----------------
__global__ __launch_bounds__(256) void rownorm_inv_bf16(
    const __hip_bfloat16* __restrict__ x, float* __restrict__ inv)
{
    const int r = blockIdx.x, t = threadIdx.x;
    const unsigned short* xr = (const unsigned short*)(x + (size_t)r * DMOD);
    float v0 = bf2f(xr[t]), v1 = bf2f(xr[t + 256]);
    __shared__ float rq[256];
    rq[t] = v0 * v0 + v1 * v1;
    __syncthreads();
    for (int off = 128; off > 0; off >>= 1) {
        if (t < off) rq[t] += rq[t + off];
        __syncthreads();
    }
    if (t == 0) inv[r] = rsqrtf(rq[0]);
}

// ---------------- fused attention: block = one class n ----------------
__global__ __launch_bounds__(256) void attn_fused(
    const __hip_bfloat16* __restrict__ qkv,   // [n*12 + qi][1536]
    __hip_bfloat16* __restrict__ out,         // [n*12 + qi][512]
    float* __restrict__ plast)                // [n][8][12]
{
    const int n = blockIdx.x, t = threadIdx.x;
    __shared__ __hip_bfloat16 S[12][1544];    // cols: 0-511 Q, 512-1023 K, 1024-1535 V
    __shared__ float P[8][12][13];

    const __hip_bfloat16* src = qkv + (size_t)n * LSEQ * (3 * DMOD);
    for (int c = t; c < 12 * 192; c += 256) {
        int r = c / 192, col = (c % 192) * 8;
        *reinterpret_cast<bf16x8*>(&S[r][col]) =
            *reinterpret_cast<const bf16x8*>(&src[(size_t)r * (3 * DMOD) + col]);
    }
    __syncthreads();

    const int h = t >> 5, l32 = t & 31;
    if (l32 < LSEQ) {
        const int qi = l32;
        float sc[LSEQ];
        #pragma unroll
        for (int ki = 0; ki < LSEQ; ki++) {
            float acc = 0.f;
            #pragma unroll
            for (int d = 0; d < DHEAD; d += 8) {
                bf16x8 qv = *reinterpret_cast<const bf16x8*>(&S[qi][h * 64 + d]);
                bf16x8 kv = *reinterpret_cast<const bf16x8*>(&S[ki][512 + h * 64 + d]);
                #pragma unroll
                for (int e = 0; e < 8; e++)
                    acc += bf2f((unsigned short)qv[e]) * bf2f((unsigned short)kv[e]);
            }
            sc[ki] = acc * 0.125f + (ki > qi ? -1e9f : 0.f);
        }
        float m = sc[0];
        #pragma unroll
        for (int ki = 1; ki < LSEQ; ki++) m = fmaxf(m, sc[ki]);
        float e[LSEQ], s = 0.f;
        #pragma unroll
        for (int ki = 0; ki < LSEQ; ki++) { e[ki] = expf(sc[ki] - m); s += e[ki]; }
        float rcp = 1.0f / s;
        #pragma unroll
        for (int ki = 0; ki < LSEQ; ki++) P[h][qi][ki] = e[ki] * rcp;
        if (qi == LSEQ - 1) {
            #pragma unroll
            for (int ki = 0; ki < LSEQ; ki++)
                plast[((size_t)n * NHEAD + h) * LSEQ + ki] = e[ki] * rcp;
        }
    }
    __syncthreads();

    #pragma unroll
    for (int dd = 0; dd < 2; dd++) {
        int d = l32 * 2 + dd;
        for (int qi = 0; qi < LSEQ; qi++) {
            float acc = 0.f;
            #pragma unroll
            for (int ki = 0; ki < LSEQ; ki++)
                acc += P[h][qi][ki] * bf2f(((const unsigned short*)&S[ki][1024 + h * 64])[d]);
            out[((size_t)(n * LSEQ + qi)) * DMOD + h * 64 + d] = __float2bfloat16(acc);
        }
    }
}

// ---------------- attr from plast ----------------
__global__ __launch_bounds__(256) void attr_kernel(
    const float* __restrict__ plast, float* __restrict__ attr)
{
    int n = blockIdx.x * 256 + threadIdx.x;
    if (n >= NCLS) return;
    float a[PFX]; float s = 0.f;
    #pragma unroll
    for (int p = 0; p < PFX; p++) {
        float acc = 0.f;
        for (int hh = 0; hh < NHEAD; hh++)
            acc += plast[((size_t)n * NHEAD + hh) * LSEQ + p];
        a[p] = acc * (1.0f / NHEAD);
        s += a[p];
    }
    #pragma unroll
    for (int p = 0; p < PFX; p++) attr[n * PFX + p] = a[p] / (s + 1e-8f);
}

// ---------------- final prep: images -> bf16, zero tf pad rows ----------------
__global__ __launch_bounds__(256) void finalize_prep(
    const float* __restrict__ images,
    __hip_bfloat16* __restrict__ img_bf,  // [256][512]
    __hip_bfloat16* __restrict__ tf_bf)   // [1024][512] (zero rows 1000..1023)
{
    int idx = blockIdx.x * 256 + threadIdx.x;
    const int NI = BIMG * DMOD, NP = 24 * DMOD;
    if (idx < NI) {
        img_bf[idx] = __float2bfloat16(images[idx]);
    } else if (idx < NI + NP) {
        int j = idx - NI;
        tf_bf[(size_t)NCLS * DMOD + j] = __float2bfloat16(0.f);
    }
}

// ---------------- attribution output ----------------
__global__ __launch_bounds__(256) void attribution_kernel(
    const float* __restrict__ attr, float* __restrict__ out2)
{
    int p = blockIdx.x, t = threadIdx.x;
    float s = 0.f;
    for (int n = t; n < NCLS; n += 256) s += attr[n * PFX + p];
    __shared__ float rq[256];
    rq[t] = s; __syncthreads();
    for (int off = 128; off > 0; off >>= 1) {
        if (t < off) rq[t] += rq[t + off];
        __syncthreads();
    }
    float mean = rq[0] * (1.0f / NCLS);
    out2[t * PFX + p] = mean;
}

extern "C" void kernel_launch(void* const* d_in, const int* in_sizes, int n_in,
                              void* d_out, int out_size, void* d_ws, size_t ws_size,
                              hipStream_t stream)
{
    const float* images = (const float*)d_in[0];
    const float* raw    = (const float*)d_in[1];
    const float* Wqkv   = (const float*)d_in[2];
    const float* bqkv   = (const float*)d_in[3];
    const float* Wo     = (const float*)d_in[4];
    const float* bo     = (const float*)d_in[5];
    const float* W1     = (const float*)d_in[6];
    const float* b1     = (const float*)d_in[7];
    const float* W2     = (const float*)d_in[8];
    const float* b2     = (const float*)d_in[9];
    const float* g1     = (const float*)d_in[10];
    const float* c1     = (const float*)d_in[11];
    const float* g2     = (const float*)d_in[12];
    const float* c2v    = (const float*)d_in[13];
    const float* tproj  = (const float*)d_in[14];
    const float* lsp    = (const float*)d_in[15];
    float* out = (float*)d_out;

    const int ROWS  = NCLS * LSEQ;   // 12000
    const int ROWSP = 12032;         // padded to 128-multiple

    // ---- workspace: fp32 scalars first, then bf16 region ----
    float* ws    = (float*)d_ws;
    float* plast = ws;                                     // 1000*8*12
    float* attr  = plast + (size_t)NCLS * NHEAD * LSEQ;    // 5120 (padded)
    float* invi  = attr + 5120;                            // 512
    float* invt  = invi + 512;                             // 1024
    __hip_bfloat16* x      = (__hip_bfloat16*)(invt + 1024);        // 12032*512 (bf16 residual)
    __hip_bfloat16* h_bf   = x + (size_t)ROWSP * DMOD;              // 12032*512
    __hip_bfloat16* u_bf   = h_bf + (size_t)ROWSP * DMOD;           // 12032*2048
    __hip_bfloat16* wT     = u_bf + (size_t)ROWSP * DFF;
    const size_t LS = (size_t)(3 * DMOD) * DMOD + (size_t)DMOD * DMOD
                    + (size_t)DMOD * DFF + (size_t)DFF * DMOD;
    __hip_bfloat16* tprojT = wT + NLAY * LS;                        // 512*512
    __hip_bfloat16* img_bf = tprojT + (size_t)DMOD * DMOD;          // 256*512
    __hip_bfloat16* tf_bf  = img_bf + (size_t)BIMG * DMOD;          // 1024*512

    for (int l = 0; l < NLAY; l++) {
        __hip_bfloat16* wqkvT = wT + l * LS;
        __hip_bfloat16* woT   = wqkvT + (size_t)(3 * DMOD) * DMOD;
        __hip_bfloat16* w1T   = woT + (size_t)DMOD * DMOD;
        __hip_bfloat16* w2T   = w1T + (size_t)DMOD * DFF;
        transposeW<<<dim3(3 * DMOD / 32, DMOD / 32), 256, 0, stream>>>(
            Wqkv + (size_t)l * DMOD * 3 * DMOD, DMOD, 3 * DMOD, wqkvT);
        transposeW<<<dim3(DMOD / 32, DMOD / 32), 256, 0, stream>>>(
            Wo + (size_t)l * DMOD * DMOD, DMOD, DMOD, woT);
        transposeW<<<dim3(DFF / 32, DMOD / 32), 256, 0, stream>>>(
            W1 + (size_t)l * DMOD * DFF, DMOD, DFF, w1T);
        transposeW<<<dim3(DMOD / 32, DFF / 32), 256, 0, stream>>>(
            W2 + (size_t)l * DFF * DMOD, DFF, DMOD, w2T);
    }
    transposeW<<<dim3(DMOD / 32, DMOD / 32), 256, 0, stream>>>(tproj, DMOD, DMOD, tprojT);

    auto run_pass = [&](bool useAttr) {
        for (int l = 0; l < NLAY; l++) {
            __hip_bfloat16* wqkvT = wT + l * LS;
            __hip_bfloat16* woT   = wqkvT + (size_t)(3 * DMOD) * DMOD;
            __hip_bfloat16* w1T   = woT + (size_t)DMOD * DMOD;
            __hip_bfloat16* w2T   = w1T + (size_t)DMOD * DFF;

            // LN1 (layer 0 materializes x = raw[*attr] in bf16 and LN in one kernel)
            if (l == 0)
                adjust_ln<<<ROWS / 4, 256, 0, stream>>>(
                    raw, useAttr ? attr : nullptr, g1, c1, x, h_bf);
            else
                ln_b16<<<ROWS / 4, 256, 0, stream>>>(x, g1 + l * DMOD, c1 + l * DMOD, h_bf);
            // qkv = h @ Wqkv + bqkv
            gemm_mfma<0><<<dim3(12, 94), 256, 0, stream>>>(
                h_bf, DMOD, wqkvT, DMOD, bqkv + l * 3 * DMOD,
                nullptr, 0, nullptr, 0, u_bf, 3 * DMOD, ROWS, DMOD,
                3 * DMOD, nullptr, nullptr, nullptr);
            attn_fused<<<NCLS, 256, 0, stream>>>(u_bf, h_bf, plast);
            // x = x + attn_out @ Wo + bo  (bf16 residual in, bf16 out)
            gemm_mfma<2><<<dim3(4, 94), 256, 0, stream>>>(
                h_bf, DMOD, woT, DMOD, bo + l * DMOD,
                x, DMOD, nullptr, 0, x, DMOD, ROWS, DMOD,
                DMOD, nullptr, nullptr, nullptr);
            ln_b16<<<ROWS / 4, 256, 0, stream>>>(x, g2 + l * DMOD, c2v + l * DMOD, h_bf);
            // g = gelu(h @ W1 + b1)
            gemm_mfma<1><<<dim3(16, 94), 256, 0, stream>>>(
                h_bf, DMOD, w1T, DMOD, b1 + l * DFF,
                nullptr, 0, nullptr, 0, u_bf, DFF, ROWS, DMOD,
                DFF, nullptr, nullptr, nullptr);
            // x = x + g @ W2 + b2
            gemm_mfma<2><<<dim3(4, 94), 256, 0, stream>>>(
                u_bf, DFF, w2T, DFF, b2 + l * DMOD,
                x, DMOD, nullptr, 0, x, DMOD, ROWS, DFF,
                DMOD, nullptr, nullptr, nullptr);
        }
    };

    run_pass(false);
    attr_kernel<<<4, 256, 0, stream>>>(plast, attr);
    run_pass(true);

    {
        int total = BIMG * DMOD + 24 * DMOD;
        finalize_prep<<<(total + 255) / 256, 256, 0, stream>>>(images, img_bf, tf_bf);
    }
    // tf = x2[:, -1, :] @ tproj  (A = x strided by 12 rows; overflow rows read
    // into adjacent h_bf allocation, outputs guarded by gm<M)
    gemm_mfma<0><<<dim3(4, 8), 256, 0, stream>>>(
        x + 11 * DMOD, LSEQ * DMOD, tprojT, DMOD, nullptr,
        nullptr, 0, nullptr, 0, tf_bf, DMOD, NCLS, DMOD,
        DMOD, nullptr, nullptr, nullptr);
    rownorm_inv_bf16<<<NCLS, 256, 0, stream>>>(tf_bf, invt);
    rownorm_inv<<<BIMG, 256, 0, stream>>>(images, invi);
    // logits = exp(ls) * invi[m] * invt[n] * (img_bf @ tf_bf^T)
    gemm_mfma<3><<<dim3(8, 2), 256, 0, stream>>>(
        img_bf, DMOD, tf_bf, DMOD, nullptr,
        nullptr, 0, out, NCLS, nullptr, 0, BIMG, DMOD,
        NCLS, invi, invt, lsp);
    attribution_kernel<<<PFX, 256, 0, stream>>>(attr, out + (size_t)BIMG * NCLS);
}